// Round 20
// baseline (82.036 us; speedup 1.0000x reference)
//
#include <hip/hip_runtime.h>
#include <math.h>

#define NB 8
#define NN 512
#define D 128
#define TIF 4         // query rows per block (= waves per block)
#define JC 64         // j-chunk size
#define NCK (NN / JC) // 8 chunks
#define LN_EPS 1e-5f
#define SCALE 0.08838834764831845f  // 1/sqrt(128)

typedef float f32x4 __attribute__((ext_vector_type(4)));

__device__ __forceinline__ float dotv(f32x4 a, f32x4 b) {
    f32x4 m = a * b;
    return m.x + m.y + m.z + m.w;
}

// ---- Single fused kernel (no k1, no workspace, no grid sync) ---------------
// Algebra: h' = alpha @ (x W^T) = (alpha @ x) W^T ; s_j = x . (W^T a_dst).
// grid: 1024 blocks x 256 thr. Prologue computes v_dst + s_j (block-local,
// x L2-shared). Flash loop = v9 body with x as PV source. Epilogue:
// y = (alpha@x)/l -> h' = y W^T -> LayerNorm.
__global__ __launch_bounds__(256, 4) void kall(
    const float* __restrict__ ef, const float* __restrict__ a_e,
    const float* __restrict__ x, const float* __restrict__ W,
    const float* __restrict__ a_dst,
    const float* __restrict__ gamma, const float* __restrict__ beta,
    float* __restrict__ out)
{
    __shared__ float sj_l[NN];                        // 2 KB
    __shared__ __align__(16) float ab[JC][TIF];       // 1 KB alpha (wave-local)
    __shared__ __align__(16) float part[4][TIF][D];   // 8 KB per-wave PV partials
    __shared__ __align__(16) float lw[4][TIF];        // per-wave l partials
    __shared__ __align__(16) float vdst[D];           // 0.5 KB W^T a_dst
    __shared__ __align__(16) float yrow[TIF][D];      // 2 KB y rows

    const int t = threadIdx.x;
    const int w = t >> 6;
    const int lane = t & 63;
    const int bid = blockIdx.x;
    const int b = bid >> 7;              // 128 blocks per batch
    const int i0 = (bid & 127) * TIF;

    // ---- chunk-0 ef prefetch (HBM latency hides under the prologue)
    const f32x4* ef4 = (const f32x4*)ef + ((size_t)b * NN + i0) * NN * 4;
    f32x4 p0 = ef4[0 * 2048 + t];
    f32x4 p1 = ef4[1 * 2048 + t];
    f32x4 p2 = ef4[2 * 2048 + t];
    f32x4 p3 = ef4[3 * 2048 + t];
    __builtin_amdgcn_sched_barrier(0);

    // ---- prologue A: v_dst = W^T a_dst (threads 0..127, coalesced over cols)
    if (t < D) {
        float v0 = 0.f, v1 = 0.f, v2 = 0.f, v3 = 0.f;
#pragma unroll 8
        for (int o = 0; o < D; o += 4) {
            v0 += a_dst[o + 0] * W[(size_t)(o + 0) * D + t];
            v1 += a_dst[o + 1] * W[(size_t)(o + 1) * D + t];
            v2 += a_dst[o + 2] * W[(size_t)(o + 2) * D + t];
            v3 += a_dst[o + 3] * W[(size_t)(o + 3) * D + t];
        }
        vdst[t] = (v0 + v1) + (v2 + v3);
    }
    __syncthreads();

    // ---- prologue B: s_j[j] = x[b,j,:] . v_dst for all 512 j
    const float* xb = x + (size_t)b * NN * D;
    {
        const f32x4* vd4 = (const f32x4*)vdst;
#pragma unroll
        for (int rep = 0; rep < 2; ++rep) {
            const int jj = t + rep * 256;
            const f32x4* xr = (const f32x4*)(xb + (size_t)jj * D);
            float s0 = 0.f, s1 = 0.f;
#pragma unroll 8
            for (int k = 0; k < 32; k += 2) {
                s0 += dotv(xr[k], vd4[k]);
                s1 += dotv(xr[k + 1], vd4[k + 1]);
            }
            sj_l[jj] = s0 + s1;
        }
    }
    __syncthreads();    // sj_l visible to all waves

    // ---- flash loop (v9 body; PV source = x) ----------------------------
    const int c = t & 3;
    const f32x4 A = ((const f32x4*)a_e)[c];
    const int jl = t >> 2;               // stage-1 column 0..63
    const int dl = (t & 31) << 2;        // PV d base
    const int g = t >> 5;                // PV j-group 0..7

    f32x4 acc0 = {0.f, 0.f, 0.f, 0.f};
    f32x4 acc1 = {0.f, 0.f, 0.f, 0.f};
    f32x4 acc2 = {0.f, 0.f, 0.f, 0.f};
    f32x4 acc3 = {0.f, 0.f, 0.f, 0.f};
    f32x4 lp   = {0.f, 0.f, 0.f, 0.f};

#pragma unroll 1
    for (int ck = 0; ck < NCK; ++ck) {
        // stage 1: alpha (no max: softmax shift-invariant; s_i cancels)
        {
            float d0 = dotv(p0, A), d1 = dotv(p1, A);
            float d2 = dotv(p2, A), d3 = dotv(p3, A);
            d0 += __shfl_xor(d0, 1); d0 += __shfl_xor(d0, 2);
            d1 += __shfl_xor(d1, 1); d1 += __shfl_xor(d1, 2);
            d2 += __shfl_xor(d2, 1); d2 += __shfl_xor(d2, 2);
            d3 += __shfl_xor(d3, 1); d3 += __shfl_xor(d3, 2);
            const float dsel = (c == 0) ? d0 : (c == 1) ? d1 : (c == 2) ? d2 : d3;
            const float al = __expf((sj_l[ck * JC + jl] + dsel) * SCALE);
            ab[jl][c] = al;              // word index == t: linear store
        }

        // issue this chunk's 8 x loads (older in FIFO than the prefetch)
        const int jl0 = g << 3;
        const int jg0 = ck * JC + jl0;
        const f32x4 hv0 = *(const f32x4*)(xb + (size_t)(jg0 + 0) * D + dl);
        const f32x4 hv1 = *(const f32x4*)(xb + (size_t)(jg0 + 1) * D + dl);
        const f32x4 hv2 = *(const f32x4*)(xb + (size_t)(jg0 + 2) * D + dl);
        const f32x4 hv3 = *(const f32x4*)(xb + (size_t)(jg0 + 3) * D + dl);
        const f32x4 hv4 = *(const f32x4*)(xb + (size_t)(jg0 + 4) * D + dl);
        const f32x4 hv5 = *(const f32x4*)(xb + (size_t)(jg0 + 5) * D + dl);
        const f32x4 hv6 = *(const f32x4*)(xb + (size_t)(jg0 + 6) * D + dl);
        const f32x4 hv7 = *(const f32x4*)(xb + (size_t)(jg0 + 7) * D + dl);
        __builtin_amdgcn_sched_barrier(0);

        // prefetch next chunk LAST (newest in FIFO)
        if (ck + 1 < NCK) {
            const int off = (ck + 1) * 256 + t;
            p0 = ef4[0 * 2048 + off];
            p1 = ef4[1 * 2048 + off];
            p2 = ef4[2 * 2048 + off];
            p3 = ef4[3 * 2048 + off];
        }
        __builtin_amdgcn_sched_barrier(0);

        // PV
        {
            const float* abp = &ab[0][0];
            const f32x4 a0v = *(const f32x4*)(abp + (jl0 + 0) * TIF);
            const f32x4 a1v = *(const f32x4*)(abp + (jl0 + 1) * TIF);
            const f32x4 a2v = *(const f32x4*)(abp + (jl0 + 2) * TIF);
            const f32x4 a3v = *(const f32x4*)(abp + (jl0 + 3) * TIF);
            const f32x4 a4v = *(const f32x4*)(abp + (jl0 + 4) * TIF);
            const f32x4 a5v = *(const f32x4*)(abp + (jl0 + 5) * TIF);
            const f32x4 a6v = *(const f32x4*)(abp + (jl0 + 6) * TIF);
            const f32x4 a7v = *(const f32x4*)(abp + (jl0 + 7) * TIF);
            acc0 += hv0 * a0v.x + hv1 * a1v.x + hv2 * a2v.x + hv3 * a3v.x
                  + hv4 * a4v.x + hv5 * a5v.x + hv6 * a6v.x + hv7 * a7v.x;
            acc1 += hv0 * a0v.y + hv1 * a1v.y + hv2 * a2v.y + hv3 * a3v.y
                  + hv4 * a4v.y + hv5 * a5v.y + hv6 * a6v.y + hv7 * a7v.y;
            acc2 += hv0 * a0v.z + hv1 * a1v.z + hv2 * a2v.z + hv3 * a3v.z
                  + hv4 * a4v.z + hv5 * a5v.z + hv6 * a6v.z + hv7 * a7v.z;
            acc3 += hv0 * a0v.w + hv1 * a1v.w + hv2 * a2v.w + hv3 * a3v.w
                  + hv4 * a4v.w + hv5 * a5v.w + hv6 * a6v.w + hv7 * a7v.w;
            lp += a0v + a1v + a2v + a3v + a4v + a5v + a6v + a7v;
        }
    }

    // ---- combine the two j-groups within each wave (lane ^ 32)
#pragma unroll
    for (int cc = 0; cc < 4; ++cc) {
        acc0[cc] += __shfl_xor(acc0[cc], 32);
        acc1[cc] += __shfl_xor(acc1[cc], 32);
        acc2[cc] += __shfl_xor(acc2[cc], 32);
        acc3[cc] += __shfl_xor(acc3[cc], 32);
        lp[cc]   += __shfl_xor(lp[cc], 32);
    }
    if (lane < 32) {
        *(f32x4*)&part[w][0][dl] = acc0;
        *(f32x4*)&part[w][1][dl] = acc1;
        *(f32x4*)&part[w][2][dl] = acc2;
        *(f32x4*)&part[w][3][dl] = acc3;
    }
    if (lane == 0) *(f32x4*)&lw[w][0] = lp;
    __syncthreads();

    // ---- y[r,:] = (sum of wave partials) / l ; wave w -> row w
    {
        const float l_r = lw[0][w] + lw[1][w] + lw[2][w] + lw[3][w];
        const float inv = 1.0f / l_r;
        const int d0 = lane, d1 = lane + 64;
        float v0 = 0.f, v1 = 0.f;
#pragma unroll
        for (int pw = 0; pw < 4; ++pw) {
            v0 += part[pw][w][d0];
            v1 += part[pw][w][d1];
        }
        yrow[w][d0] = v0 * inv;
        yrow[w][d1] = v1 * inv;
    }
    __syncthreads();

    // ---- h'[w,d] = y[w,:] . W[d,:] (W L2-hot) -> LayerNorm -> out
    {
        const int d0 = lane, d1 = lane + 64;
        const f32x4* yv  = (const f32x4*)yrow[w];
        const f32x4* Wd0 = (const f32x4*)(W + (size_t)d0 * D);
        const f32x4* Wd1 = (const f32x4*)(W + (size_t)d1 * D);
        float h0a = 0.f, h0b = 0.f, h1a = 0.f, h1b = 0.f;
#pragma unroll 8
        for (int k = 0; k < 32; k += 2) {
            const f32x4 y0 = yv[k], y1 = yv[k + 1];
            h0a += dotv(y0, Wd0[k]);
            h0b += dotv(y1, Wd0[k + 1]);
            h1a += dotv(y0, Wd1[k]);
            h1b += dotv(y1, Wd1[k + 1]);
        }
        const float h0 = h0a + h0b, h1 = h1a + h1b;
        float s = h0 + h1, qq = h0 * h0 + h1 * h1;
#pragma unroll
        for (int mm = 32; mm >= 1; mm >>= 1) {
            s += __shfl_xor(s, mm);
            qq += __shfl_xor(qq, mm);
        }
        const float mu = s * (1.f / 128.f);
        const float var = qq * (1.f / 128.f) - mu * mu;
        const float rs = rsqrtf(var + LN_EPS);
        const size_t ob = ((size_t)(b * NN + i0 + w)) * D;
        out[ob + d0] = (h0 - mu) * rs * gamma[d0] + beta[d0];
        out[ob + d1] = (h1 - mu) * rs * gamma[d1] + beta[d1];
    }
}

extern "C" void kernel_launch(void* const* d_in, const int* in_sizes, int n_in,
                              void* d_out, int out_size, void* d_ws, size_t ws_size,
                              hipStream_t stream) {
    const float* x     = (const float*)d_in[0];
    const float* ef    = (const float*)d_in[1];
    const float* W     = (const float*)d_in[2];
    const float* a_dst = (const float*)d_in[4];
    const float* a_e   = (const float*)d_in[5];
    const float* gamma = (const float*)d_in[6];
    const float* beta  = (const float*)d_in[7];
    float* out = (float*)d_out;

    kall<<<NB * NN / TIF, 256, 0, stream>>>(ef, a_e, x, W, a_dst,
                                            gamma, beta, out);
}

// Round 21
// 47.508 us; speedup vs baseline: 1.7268x; 1.7268x over previous
//
#include <hip/hip_runtime.h>
#include <math.h>

#define NB 8
#define NN 512
#define D 128
#define TIF 4         // query rows per fused block (= waves per block)
#define JC 64         // j-chunk size
#define NCK (NN / JC) // 8 chunks
#define K1R 8         // rows per k1 block
#define LN_EPS 1e-5f
#define SCALE 0.08838834764831845f  // 1/sqrt(128)

typedef float f32x4 __attribute__((ext_vector_type(4)));

__device__ __forceinline__ float dotv(f32x4 a, f32x4 b) {
    f32x4 m = a * b;
    return m.x + m.y + m.z + m.w;
}
__device__ __forceinline__ float dot4(float4 a, float4 b) {
    return a.x * b.x + a.y * b.y + a.z * b.z + a.w * b.w;
}

// ---------------- Kernel 1: h = x @ W^T, s_j ---------------------------------
// (v7 k1 minus the dead s_i computation — kfused's softmax is shift-invariant
// and s_i cancels exactly, so it was never read after round 13.)
__global__ __launch_bounds__(256) void k1_proj(
    const float* __restrict__ x, const float* __restrict__ W,
    const float* __restrict__ a_dst,
    float* __restrict__ h_ws, float* __restrict__ sj_ws)
{
    __shared__ __align__(16) float4 Wl[128][32];   // [o][q ^ (o&7)] swizzle
    __shared__ __align__(16) float4 xl[K1R][32];
    __shared__ float redk[K1R][2];

    const int t = threadIdx.x;
    const int row0 = blockIdx.x * K1R;

    const float4* Wg = (const float4*)W;
#pragma unroll
    for (int k = 0; k < 16; ++k) {
        const int f = t + 256 * k;
        const int o = f >> 5, q = f & 31;
        Wl[o][q ^ (o & 7)] = Wg[f];
    }
    xl[t >> 5][t & 31] = ((const float4*)(x + (size_t)row0 * D))[t];
    __syncthreads();

    const int o = t & 127;
    const int rb = (t >> 7) * (K1R / 2);
    float acc[K1R / 2] = {0.f, 0.f, 0.f, 0.f};
#pragma unroll
    for (int q = 0; q < 32; ++q) {
        const float4 wv = Wl[o][q ^ (o & 7)];
#pragma unroll
        for (int r = 0; r < K1R / 2; ++r) acc[r] += dot4(wv, xl[rb + r][q]);
    }
    const float ad = a_dst[o];
#pragma unroll
    for (int r = 0; r < K1R / 2; ++r) {
        h_ws[(size_t)(row0 + rb + r) * D + o] = acc[r];
        float vd = acc[r] * ad;
#pragma unroll
        for (int m = 32; m >= 1; m >>= 1) vd += __shfl_xor(vd, m);
        if ((t & 63) == 0) redk[rb + r][(t >> 6) & 1] = vd;
    }
    __syncthreads();
    if (t < K1R) sj_ws[row0 + t] = redk[t][0] + redk[t][1];
}

// ------- Fused flash v7 (best, round 16): barrier-free wave-local loop ------
// grid: 1024 blocks, block: 256 (4 waves). Chunk loop is wave-local:
// stage-1 writer (t -> ab[t>>2]) and PV reader (wave w -> j in [16w,16w+16))
// are the same wave; no in-loop barriers, no ping-pong. Depth-1 prefetch,
// 9 live f32x4 (the proven non-spilling shape).
__global__ __launch_bounds__(256, 4) void kfused(
    const float* __restrict__ ef, const float* __restrict__ a_e,
    const float* __restrict__ gamma, const float* __restrict__ beta,
    const float* __restrict__ h_ws,
    const float* __restrict__ sj_ws, float* __restrict__ out)
{
    __shared__ float sj_l[NN];                        // 2 KB
    __shared__ __align__(16) float ab[JC][TIF];       // 1 KB alpha (wave-local)
    __shared__ __align__(16) float part[4][TIF][D];   // 8 KB per-wave PV partials
    __shared__ __align__(16) float lw[4][TIF];        // per-wave l partials

    const int t = threadIdx.x;
    const int w = t >> 6;
    const int lane = t & 63;
    const int bid = blockIdx.x;
    const int b = bid >> 7;              // 128 blocks per batch
    const int i0 = (bid & 127) * TIF;

    sj_l[t] = sj_ws[b * NN + t];
    sj_l[t + 256] = sj_ws[b * NN + t + 256];

    const int c = t & 3;
    const f32x4 A = ((const f32x4*)a_e)[c];
    const f32x4* ef4 = (const f32x4*)ef + ((size_t)b * NN + i0) * NN * 4;

    const int jl = t >> 2;               // stage-1 column 0..63
    const int dl = (t & 31) << 2;        // PV d base
    const int g = t >> 5;                // PV j-group 0..7
    const float* hb = h_ws + (size_t)b * NN * D;

    f32x4 acc0 = {0.f, 0.f, 0.f, 0.f};
    f32x4 acc1 = {0.f, 0.f, 0.f, 0.f};
    f32x4 acc2 = {0.f, 0.f, 0.f, 0.f};
    f32x4 acc3 = {0.f, 0.f, 0.f, 0.f};
    f32x4 lp   = {0.f, 0.f, 0.f, 0.f};   // per-row l partial (wave-own j's)

    // prefetch chunk 0 (plain loads)
    f32x4 p0 = ef4[0 * 2048 + t];
    f32x4 p1 = ef4[1 * 2048 + t];
    f32x4 p2 = ef4[2 * 2048 + t];
    f32x4 p3 = ef4[3 * 2048 + t];

    __syncthreads();    // sj_l visible (only cross-wave dependency in the loop)

    for (int ck = 0; ck < NCK; ++ck) {
        // ---- stage 1: alpha for this wave's 16 columns (no max subtraction:
        // softmax is exactly shift-invariant; s_i cancels; |e| small).
        {
            float d0 = dotv(p0, A), d1 = dotv(p1, A);
            float d2 = dotv(p2, A), d3 = dotv(p3, A);
            d0 += __shfl_xor(d0, 1); d0 += __shfl_xor(d0, 2);
            d1 += __shfl_xor(d1, 1); d1 += __shfl_xor(d1, 2);
            d2 += __shfl_xor(d2, 1); d2 += __shfl_xor(d2, 2);
            d3 += __shfl_xor(d3, 1); d3 += __shfl_xor(d3, 2);
            const float dsel = (c == 0) ? d0 : (c == 1) ? d1 : (c == 2) ? d2 : d3;
            const float al = __expf((sj_l[ck * JC + jl] + dsel) * SCALE);
            ab[jl][c] = al;              // word index == t: linear store
        }
        // ---- prefetch next chunk (in flight across this chunk's PV)
        if (ck + 1 < NCK) {
            const int off = (ck + 1) * 256 + t;
            p0 = ef4[0 * 2048 + off];
            p1 = ef4[1 * 2048 + off];
            p2 = ef4[2 * 2048 + off];
            p3 = ef4[3 * 2048 + off];
        }

        // ---- PV: this wave's 16 j (g = 2w, 2w+1 per thread-half), 4 d-cols.
        {
            const float* abp = &ab[0][0];
#pragma unroll
            for (int jt = 0; jt < 2; ++jt) {
                const int j0 = (g << 3) + (jt << 2);
                const int jg = ck * JC + j0;
                const f32x4 hv0 = *(const f32x4*)(hb + (size_t)(jg + 0) * D + dl);
                const f32x4 hv1 = *(const f32x4*)(hb + (size_t)(jg + 1) * D + dl);
                const f32x4 hv2 = *(const f32x4*)(hb + (size_t)(jg + 2) * D + dl);
                const f32x4 hv3 = *(const f32x4*)(hb + (size_t)(jg + 3) * D + dl);
                const f32x4 a0v = *(const f32x4*)(abp + (j0 + 0) * TIF);
                const f32x4 a1v = *(const f32x4*)(abp + (j0 + 1) * TIF);
                const f32x4 a2v = *(const f32x4*)(abp + (j0 + 2) * TIF);
                const f32x4 a3v = *(const f32x4*)(abp + (j0 + 3) * TIF);
                acc0 += hv0 * a0v.x + hv1 * a1v.x + hv2 * a2v.x + hv3 * a3v.x;
                acc1 += hv0 * a0v.y + hv1 * a1v.y + hv2 * a2v.y + hv3 * a3v.y;
                acc2 += hv0 * a0v.z + hv1 * a1v.z + hv2 * a2v.z + hv3 * a3v.z;
                acc3 += hv0 * a0v.w + hv1 * a1v.w + hv2 * a2v.w + hv3 * a3v.w;
                lp += a0v + a1v + a2v + a3v;
            }
        }
    }

    // ---- combine the two j-groups within each wave (lane ^ 32)
#pragma unroll
    for (int cc = 0; cc < 4; ++cc) {
        acc0[cc] += __shfl_xor(acc0[cc], 32);
        acc1[cc] += __shfl_xor(acc1[cc], 32);
        acc2[cc] += __shfl_xor(acc2[cc], 32);
        acc3[cc] += __shfl_xor(acc3[cc], 32);
        lp[cc]   += __shfl_xor(lp[cc], 32);
    }
    if (lane < 32) {
        *(f32x4*)&part[w][0][dl] = acc0;
        *(f32x4*)&part[w][1][dl] = acc1;
        *(f32x4*)&part[w][2][dl] = acc2;
        *(f32x4*)&part[w][3][dl] = acc3;
    }
    if (lane == 0) *(f32x4*)&lw[w][0] = lp;
    __syncthreads();

    // ---- LayerNorm: wave w -> row w
    {
        const float l_r = lw[0][w] + lw[1][w] + lw[2][w] + lw[3][w];
        const float inv = 1.0f / l_r;
        const int d0 = lane, d1 = lane + 64;
        float v0 = 0.f, v1 = 0.f;
#pragma unroll
        for (int pw = 0; pw < 4; ++pw) {
            v0 += part[pw][w][d0];
            v1 += part[pw][w][d1];
        }
        v0 *= inv; v1 *= inv;
        float s = v0 + v1, qq = v0 * v0 + v1 * v1;
#pragma unroll
        for (int mm = 32; mm >= 1; mm >>= 1) {
            s += __shfl_xor(s, mm);
            qq += __shfl_xor(qq, mm);
        }
        const float mu = s * (1.f / 128.f);
        const float var = qq * (1.f / 128.f) - mu * mu;
        const float rs = rsqrtf(var + LN_EPS);
        const size_t ob = ((size_t)(b * NN + i0 + w)) * D;
        out[ob + d0] = (v0 - mu) * rs * gamma[d0] + beta[d0];
        out[ob + d1] = (v1 - mu) * rs * gamma[d1] + beta[d1];
    }
}

extern "C" void kernel_launch(void* const* d_in, const int* in_sizes, int n_in,
                              void* d_out, int out_size, void* d_ws, size_t ws_size,
                              hipStream_t stream) {
    const float* x     = (const float*)d_in[0];
    const float* ef    = (const float*)d_in[1];
    const float* W     = (const float*)d_in[2];
    const float* a_dst = (const float*)d_in[4];
    const float* a_e   = (const float*)d_in[5];
    const float* gamma = (const float*)d_in[6];
    const float* beta  = (const float*)d_in[7];
    float* out = (float*)d_out;

    float* h_ws  = (float*)d_ws;                       // 2 MiB
    float* sj_ws = h_ws + (size_t)NB * NN * D;         // 16 KiB

    k1_proj<<<NB * NN / K1R, 256, 0, stream>>>(x, W, a_dst, h_ws, sj_ws);
    kfused<<<NB * NN / TIF, 256, 0, stream>>>(ef, a_e, gamma, beta,
                                              h_ws, sj_ws, out);
}